// Round 2
// baseline (503.698 us; speedup 1.0000x reference)
//
#include <hip/hip_runtime.h>
#include <cstdint>
#include <cstddef>

// ---------------- types ----------------
typedef __attribute__((ext_vector_type(8))) _Float16 half8;   // MFMA f16 A/B frag (4 VGPRs)
typedef __attribute__((ext_vector_type(4))) _Float16 half4;
typedef __attribute__((ext_vector_type(4))) float    floatx4; // MFMA C/D frag

static constexpr int B_ROWS = 16384;
static constexpr int IN_DIM = 256;
static constexpr int H_DIM  = 512;
static constexpr int NB     = 16;

__device__ __forceinline__ float fast_tanh(float x) {
  float ax = fabsf(x);
  float e  = __expf(2.0f * ax);             // e >= 1, inf-safe
  float t  = 1.0f - 2.0f / (e + 1.0f);
  return copysignf(t, x);
}

// async global->LDS, 16B per lane; LDS dest must be wave-uniform base + lane*16
__device__ __forceinline__ void gld16(const void* g, void* l) {
  __builtin_amdgcn_global_load_lds(
      (const __attribute__((address_space(1))) unsigned int*)g,
      (__attribute__((address_space(3))) unsigned int*)l, 16, 0, 0);
}

// ---------------- prep: x column-stats partials (blocks 0..127) + coeff cvt (blocks 128+) ----
// cvt folds K_n = exp(-2 c_n^2) into the fp16 coeffs.
__global__ __launch_bounds__(256) void prep_k(const float* __restrict__ c1, _Float16* __restrict__ d1, size_t n41,
                                              const float* __restrict__ c2, _Float16* __restrict__ d2, size_t n42,
                                              const float* __restrict__ X,
                                              float* __restrict__ ps, float* __restrict__ ps2) {
  const int bx = blockIdx.x;
  if (bx < 128) {
    // ---- stats on X: cols=256 (4 col-groups of 64), 32 row-segs of 512 ----
    int c     = (bx & 3) * 64 + (threadIdx.x & 63);
    int chunk = threadIdx.x >> 6;
    int seg   = bx >> 2;
    int r0    = seg * 512;
    double s = 0.0, s2 = 0.0;
    for (int r = r0 + chunk; r < r0 + 512; r += 4) {
      float v = X[(size_t)r * IN_DIM + c];
      s += v; s2 += (double)v * (double)v;
    }
    __shared__ float Ls[256], Ls2[256];
    Ls[threadIdx.x] = (float)s; Ls2[threadIdx.x] = (float)s2;
    __syncthreads();
    if (chunk == 0) {
      int cl = threadIdx.x;
      float a  = Ls[cl]  + Ls[cl + 64]  + Ls[cl + 128]  + Ls[cl + 192];
      float b  = Ls2[cl] + Ls2[cl + 64] + Ls2[cl + 128] + Ls2[cl + 192];
      ps [(size_t)seg * IN_DIM + c] = a;
      ps2[(size_t)seg * IN_DIM + c] = b;
    }
  } else {
    // ---- coeff conversion, grid-stride over remaining blocks ----
    size_t tot = n41 + n42;
    int nb_blocks = gridDim.x - 128;
    for (size_t i = (size_t)(bx - 128) * 256 + threadIdx.x; i < tot;
         i += (size_t)nb_blocks * 256) {
      const float4* sp; half4* dp; size_t j;
      if (i < n41) { sp = (const float4*)c1; dp = (half4*)d1; j = i; }
      else         { sp = (const float4*)c2; dp = (half4*)d2; j = i - n41; }
      float4 v = sp[j];
      int nb = (int)((j << 2) & 15);
      half4 r;
      float e0 = -2.f + (float)(nb + 0) * (4.f / 15.f);
      float e1 = -2.f + (float)(nb + 1) * (4.f / 15.f);
      float e2 = -2.f + (float)(nb + 2) * (4.f / 15.f);
      float e3 = -2.f + (float)(nb + 3) * (4.f / 15.f);
      r[0] = (_Float16)(v.x * __expf(-2.f * e0 * e0));
      r[1] = (_Float16)(v.y * __expf(-2.f * e1 * e1));
      r[2] = (_Float16)(v.z * __expf(-2.f * e2 * e2));
      r[3] = (_Float16)(v.w * __expf(-2.f * e3 * e3));
      dp[j] = r;
    }
  }
}

// ---------------- stats finalize (float partials) ----------------
__global__ void stats_final_k(const float* __restrict__ ps,
                              const float* __restrict__ ps2,
                              int segs, int cols, int rows,
                              float* __restrict__ mu, float* __restrict__ isd) {
  int c = blockIdx.x * blockDim.x + threadIdx.x;
  if (c >= cols) return;
  double s = 0.0, s2 = 0.0;
  for (int g = 0; g < segs; g++) { s += ps[(size_t)g * cols + c]; s2 += ps2[(size_t)g * cols + c]; }
  double mean = s / rows;
  double var  = (s2 - s * s / rows) / (rows - 1);   // ddof=1
  if (var < 0.0) var = 0.0;
  float sd = (float)sqrt(var);
  mu[c]  = (float)mean;
  isd[c] = 1.0f / (sd + 1e-6f);
}

// ---------------- fused normalize+expand+GEMM+tanh + column-stats partials ----------------
// H[b, o] = tanh( sum_k basis(xn[b, k/16])_[k%16] * Cb[o, k] ),  K = C*16
// 128x128 tile, BK=64, double-buffered. R8: 256 -> 512 threads (8 waves, 2m x 4n).
// R7 post-mortem: step time 3337 cyc vs ~1242 MFMA + ~1250 VALU -> ~1.5-2k cyc/step
// with BOTH resident waves stalled (2 waves/SIMD at Occupancy 22%). Grid (512 blocks)
// caps blocks/CU at 2 and LDS (66 KB) forbids a 3rd, so raise waves/block instead:
// 512 thr x 2 blocks/CU = 16 waves/CU = 4/SIMD. Same total pipe work, same barrier
// count, 2x latency-hiding pool at every drain point.
// A: K-major LDS (2-way-free frag reads). B: XOR swizzle seg' = sl ^ ((row>>1)&7)
// (coalesced DMA + 2-way-free frag reads). s_setprio(1) around MFMA cluster (T5).
// Epilogue: fused per-block column sums of h and h^2 -> psum/psum2 for next layer's stats.
__global__ __launch_bounds__(512, 4) void kan_gemm_fused(const float* __restrict__ X,   // [B, C]
                                                         const float* __restrict__ mu,
                                                         const float* __restrict__ isd,
                                                         const _Float16* __restrict__ Bm, // [512, C*16]
                                                         float* __restrict__ Hout,        // [B, 512]
                                                         float* __restrict__ psum,        // [128, 512]
                                                         float* __restrict__ psum2,       // [128, 512]
                                                         int C) {
  const int K = C << 4;
  const int steps = K >> 6;                 // BK = 64
  __shared__ __align__(16) _Float16 As[2][128 * 64];   // 32 KB; chunk = kseg*128 + row, kseg 0..7
  __shared__ __align__(16) _Float16 Bs[2][128 * 64];   // 32 KB; chunk = row*8 + swizzled seg
  __shared__ float Rs1[2][128], Rs2[2][128];           //  2 KB epilogue reduction
  const int tid  = threadIdx.x;
  const int w = tid >> 6, lane = tid & 63;
  const int wm = w & 1, wn = w >> 1;        // 2x4 wave grid: wave owns 64 rows x 32 cols
  const int lrow = lane & 15, quad = lane >> 4;
  const int row0 = blockIdx.x * 128;
  const int col0 = blockIdx.y * 128;

  // ---- B staging: buffer = 1024 chunks of 16B; thread owns chunks tid, tid+512.
  //      chunk c = row*8 + sl holds global seg = sl ^ ((row>>1)&7); the two chunks'
  //      rows differ by 64 so ((row>>1)&7) is invariant -> one seg for both.
  const int s_row = tid >> 3;               // 0..63
  const int s_sl  = tid & 7;
  const int s_seg = s_sl ^ ((s_row >> 1) & 7);
  const _Float16* gB = Bm + (size_t)(col0 + s_row) * K + s_seg * 8;

  // ---- A expansion: thread -> row = tid>>2, col-slot eh = tid&3; step k covers
  //      x-cols [4k, 4k+4); this thread expands col 4k+eh -> ksegs 2eh, 2eh+1.
  const int erow = tid >> 2, eh = tid & 3;
  const float* xp  = X   + (size_t)(row0 + erow) * C + eh;  // step k: xp[4k]
  const float* mup = mu  + eh;
  const float* isp = isd + eh;

  floatx4 acc[4][2] = {};

  auto expand_store = [&](float xr, float mm, float ii, int bufi) {
    float xn = fminf(fmaxf((xr - mm) * ii, -3.f), 3.f);
    float Wv = __expf(-2.f * xn * xn - 8.f * xn);
    float g  = __expf((16.f / 15.f) * xn);
    half8 h0, h1;
    float p = Wv;
#pragma unroll
    for (int n = 0; n < 8; n++) { h0[n] = (_Float16)p; p *= g; }
#pragma unroll
    for (int n = 0; n < 8; n++) { h1[n] = (_Float16)p; p *= g; }
    int ks0 = 2 * eh;
    *(half8*)&As[bufi][(size_t)(ks0 * 128 + erow) * 8]       = h0;
    *(half8*)&As[bufi][(size_t)((ks0 + 1) * 128 + erow) * 8] = h1;
  };

  // ---- prologue: fill buffer 0 ----
  gld16(gB, &Bs[0][(size_t)tid * 8]);
  gld16(gB + (size_t)64 * K, &Bs[0][(size_t)(tid + 512) * 8]);
  expand_store(xp[0], mup[0], isp[0], 0);
  float xv = 0.f, mv = 0.f, iv = 0.f;
  if (steps > 1) { xv = xp[4]; mv = mup[4]; iv = isp[4]; }
  __syncthreads();

  // ---- main loop: one barrier per BK=64 step; DMA+expand for k+1 issued before MFMA of k ----
  for (int k = 0; k < steps; k++) {
    const int buf = k & 1, nb = buf ^ 1;
    if (k + 1 < steps) {
      gld16(gB + (size_t)(k + 1) * 64, &Bs[nb][(size_t)tid * 8]);
      gld16(gB + (size_t)(k + 1) * 64 + (size_t)64 * K, &Bs[nb][(size_t)(tid + 512) * 8]);
      expand_store(xv, mv, iv, nb);
      if (k + 2 < steps) {
        xv = xp[4 * (k + 2)];
        mv = mup[4 * (k + 2)];
        iv = isp[4 * (k + 2)];
      }
    }
    __builtin_amdgcn_s_setprio(1);
#pragma unroll
    for (int ks = 0; ks < 2; ks++) {
      half8 af[4], bf[2];
#pragma unroll
      for (int t = 0; t < 4; t++) {
        int arow = wm * 64 + t * 16 + lrow;
        af[t] = *(const half8*)&As[buf][(size_t)((4 * ks + quad) * 128 + arow) * 8];
      }
#pragma unroll
      for (int t = 0; t < 2; t++) {
        int brow = wn * 32 + t * 16 + lrow;
        int bchunk = brow * 8 + ((4 * ks + quad) ^ ((brow >> 1) & 7));
        bf[t] = *(const half8*)&Bs[buf][(size_t)bchunk * 8];
      }
#pragma unroll
      for (int tm = 0; tm < 4; tm++)
#pragma unroll
        for (int tn = 0; tn < 2; tn++)
          acc[tm][tn] = __builtin_amdgcn_mfma_f32_16x16x32_f16(af[tm], bf[tn], acc[tm][tn], 0, 0, 0);
    }
    __builtin_amdgcn_s_setprio(0);
    __syncthreads();
  }

  // ---- epilogue: C/D layout col=lane&15, row=quad*4+reg; fused tanh + column partial sums ----
  float s1[2] = {0.f, 0.f}, s2v[2] = {0.f, 0.f};
#pragma unroll
  for (int tm = 0; tm < 4; tm++) {
#pragma unroll
    for (int tn = 0; tn < 2; tn++) {
      int gcol = col0 + wn * 32 + tn * 16 + lrow;
#pragma unroll
      for (int r = 0; r < 4; r++) {
        int grow = row0 + wm * 64 + tm * 16 + quad * 4 + r;
        float v = fast_tanh(acc[tm][tn][r]);
        Hout[(size_t)grow * H_DIM + gcol] = v;
        s1[tn] += v; s2v[tn] += v * v;
      }
    }
  }
  // reduce over quad (rows within the wave's 64-row span)
#pragma unroll
  for (int tn = 0; tn < 2; tn++) {
    s1[tn]  += __shfl_xor(s1[tn], 16);  s1[tn]  += __shfl_xor(s1[tn], 32);
    s2v[tn] += __shfl_xor(s2v[tn], 16); s2v[tn] += __shfl_xor(s2v[tn], 32);
  }
  if (quad == 0) {
#pragma unroll
    for (int tn = 0; tn < 2; tn++) {
      Rs1[wm][wn * 32 + tn * 16 + lrow] = s1[tn];
      Rs2[wm][wn * 32 + tn * 16 + lrow] = s2v[tn];
    }
  }
  __syncthreads();
  if (tid < 128) {
    psum [(size_t)blockIdx.x * H_DIM + col0 + tid] = Rs1[0][tid] + Rs1[1][tid];
    psum2[(size_t)blockIdx.x * H_DIM + col0 + tid] = Rs2[0][tid] + Rs2[1][tid];
  }
}

// ---------------- layer 3 (out dim 1) + skip, fp32, normalize fused ----------------
__global__ __launch_bounds__(256) void layer3_k(const float* __restrict__ H2,
                                                const float* __restrict__ mu,
                                                const float* __restrict__ isd,
                                                const float* __restrict__ C3,
                                                const float* __restrict__ X,
                                                const float* __restrict__ SW,
                                                const float* __restrict__ SB,
                                                float* __restrict__ OUT) {
  int w = threadIdx.x >> 6, lane = threadIdx.x & 63;
  float Kn[NB];
#pragma unroll
  for (int n = 0; n < NB; n++) {
    float c = -2.f + (float)n * (4.f / 15.f);
    Kn[n] = __expf(-2.f * c * c);
  }
  float sb0 = SB[0];
  int row_base = blockIdx.x * 16 + w * 4;
  for (int r = 0; r < 4; r++) {
    int row = row_base + r;
    float s = 0.f;
#pragma unroll
    for (int j = 0; j < 8; j++) {
      int i = lane + 64 * j;
      float hv = H2[(size_t)row * H_DIM + i];
      float xn = fminf(fmaxf((hv - mu[i]) * isd[i], -3.f), 3.f);
      float Wf = __expf(-2.f * xn * xn - 8.f * xn);
      float gf = __expf((16.f / 15.f) * xn);
      const floatx4* cp = (const floatx4*)(C3 + (size_t)i * NB);
      floatx4 c0 = cp[0], c1 = cp[1], c2 = cp[2], c3 = cp[3];
      float p = Wf;
#pragma unroll
      for (int n = 0; n < 4; n++) { s += p * Kn[n]      * c0[n]; p *= gf; }
#pragma unroll
      for (int n = 0; n < 4; n++) { s += p * Kn[n + 4]  * c1[n]; p *= gf; }
#pragma unroll
      for (int n = 0; n < 4; n++) { s += p * Kn[n + 8]  * c2[n]; p *= gf; }
#pragma unroll
      for (int n = 0; n < 4; n++) { s += p * Kn[n + 12] * c3[n]; p *= gf; }
    }
#pragma unroll
    for (int j = 0; j < 4; j++) {
      int i = lane + 64 * j;
      s += X[(size_t)row * IN_DIM + i] * SW[i];
    }
#pragma unroll
    for (int off = 32; off > 0; off >>= 1) s += __shfl_down(s, off);
    if (lane == 0) OUT[row] = s + sb0;
  }
}

// ---------------- launcher ----------------
extern "C" void kernel_launch(void* const* d_in, const int* in_sizes, int n_in,
                              void* d_out, int out_size, void* d_ws, size_t ws_size,
                              hipStream_t stream) {
  const float* x  = (const float*)d_in[0];   // [16384, 256]
  const float* c1 = (const float*)d_in[1];   // [512, 256, 16]
  const float* c2 = (const float*)d_in[2];   // [512, 512, 16]
  const float* c3 = (const float*)d_in[3];   // [1, 512, 16]
  const float* sw = (const float*)d_in[4];   // [1, 256]
  const float* sb = (const float*)d_in[5];   // [1]
  float* out = (float*)d_out;

  const int B = B_ROWS, IN = IN_DIM, H = H_DIM;

  char* ws = (char*)d_ws;
  size_t off = 0;
  auto alloc = [&](size_t bytes) -> void* {
    void* p = ws + off;
    off += (bytes + 255) & ~(size_t)255;
    return p;
  };
  _Float16* C1h = (_Float16*)alloc((size_t)H * IN * NB * 2);  //  4 MB
  _Float16* C2h = (_Float16*)alloc((size_t)H * H  * NB * 2);  //  8 MB
  float* H1 = (float*)alloc((size_t)B * H * 4);               // 32 MB
  float* H2 = (float*)alloc((size_t)B * H * 4);               // 32 MB
  float* ps  = (float*)alloc(128 * 512 * 4);                  // 256 KB
  float* ps2 = (float*)alloc(128 * 512 * 4);
  float* mu  = (float*)alloc(512 * 4);
  float* isd = (float*)alloc(512 * 4);

  // ---- prep: x-stats partials + coeff cvt in one dispatch ----
  prep_k<<<128 + 1024, 256, 0, stream>>>(c1, C1h, (size_t)H * IN * NB / 4,
                                         c2, C2h, (size_t)H * H * NB / 4,
                                         x, ps, ps2);
  stats_final_k<<<1, 256, 0, stream>>>(ps, ps2, 32, IN, B, mu, isd);

  // ---- layer 1 (C=256, K=4096); epilogue emits H1 column partials ----
  kan_gemm_fused<<<dim3(B / 128, 4), 512, 0, stream>>>(x, mu, isd, C1h, H1, ps, ps2, IN);
  stats_final_k<<<2, 256, 0, stream>>>(ps, ps2, 128, H, B, mu, isd);

  // ---- layer 2 (C=512, K=8192); epilogue emits H2 column partials ----
  kan_gemm_fused<<<dim3(B / 128, 4), 512, 0, stream>>>(H1, mu, isd, C2h, H2, ps, ps2, H);
  stats_final_k<<<2, 256, 0, stream>>>(ps, ps2, 128, H, B, mu, isd);

  // ---- layer 3 + skip (normalize fused) ----
  layer3_k<<<B / 16, 256, 0, stream>>>(H2, mu, isd, c3, x, sw, sb, out);
}

// Round 4
// 455.633 us; speedup vs baseline: 1.1055x; 1.1055x over previous
//
#include <hip/hip_runtime.h>
#include <cstdint>
#include <cstddef>

// ---------------- types ----------------
typedef __attribute__((ext_vector_type(8))) _Float16 half8;   // MFMA f16 A/B frag (4 VGPRs)
typedef __attribute__((ext_vector_type(4))) _Float16 half4;
typedef __attribute__((ext_vector_type(2))) __fp16   fp16x2;  // cvt_pkrtz result type
typedef __attribute__((ext_vector_type(4))) float    floatx4; // MFMA C/D frag

static constexpr int B_ROWS = 16384;
static constexpr int IN_DIM = 256;
static constexpr int H_DIM  = 512;
static constexpr int NB     = 16;

__device__ __forceinline__ float fast_tanh(float x) {
  float ax = fabsf(x);
  float e  = __expf(2.0f * ax);             // e >= 1, inf-safe
  float t  = 1.0f - 2.0f / (e + 1.0f);
  return copysignf(t, x);
}

// async global->LDS, 16B per lane; LDS dest must be wave-uniform base + lane*16
__device__ __forceinline__ void gld16(const void* g, void* l) {
  __builtin_amdgcn_global_load_lds(
      (const __attribute__((address_space(1))) unsigned int*)g,
      (__attribute__((address_space(3))) unsigned int*)l, 16, 0, 0);
}

// ---------------- prep: x column-stats partials (blocks 0..127) + coeff cvt (blocks 128+) ----
// cvt folds K_n = exp(-2 c_n^2) into the fp16 coeffs.
__global__ __launch_bounds__(256) void prep_k(const float* __restrict__ c1, _Float16* __restrict__ d1, size_t n41,
                                              const float* __restrict__ c2, _Float16* __restrict__ d2, size_t n42,
                                              const float* __restrict__ X,
                                              float* __restrict__ ps, float* __restrict__ ps2) {
  const int bx = blockIdx.x;
  if (bx < 128) {
    // ---- stats on X: cols=256 (4 col-groups of 64), 32 row-segs of 512 ----
    int c     = (bx & 3) * 64 + (threadIdx.x & 63);
    int chunk = threadIdx.x >> 6;
    int seg   = bx >> 2;
    int r0    = seg * 512;
    double s = 0.0, s2 = 0.0;
    for (int r = r0 + chunk; r < r0 + 512; r += 4) {
      float v = X[(size_t)r * IN_DIM + c];
      s += v; s2 += (double)v * (double)v;
    }
    __shared__ float Ls[256], Ls2[256];
    Ls[threadIdx.x] = (float)s; Ls2[threadIdx.x] = (float)s2;
    __syncthreads();
    if (chunk == 0) {
      int cl = threadIdx.x;
      float a  = Ls[cl]  + Ls[cl + 64]  + Ls[cl + 128]  + Ls[cl + 192];
      float b  = Ls2[cl] + Ls2[cl + 64] + Ls2[cl + 128] + Ls2[cl + 192];
      ps [(size_t)seg * IN_DIM + c] = a;
      ps2[(size_t)seg * IN_DIM + c] = b;
    }
  } else {
    // ---- coeff conversion, grid-stride over remaining blocks ----
    size_t tot = n41 + n42;
    int nb_blocks = gridDim.x - 128;
    for (size_t i = (size_t)(bx - 128) * 256 + threadIdx.x; i < tot;
         i += (size_t)nb_blocks * 256) {
      const float4* sp; half4* dp; size_t j;
      if (i < n41) { sp = (const float4*)c1; dp = (half4*)d1; j = i; }
      else         { sp = (const float4*)c2; dp = (half4*)d2; j = i - n41; }
      float4 v = sp[j];
      int nb = (int)((j << 2) & 15);
      half4 r;
      float e0 = -2.f + (float)(nb + 0) * (4.f / 15.f);
      float e1 = -2.f + (float)(nb + 1) * (4.f / 15.f);
      float e2 = -2.f + (float)(nb + 2) * (4.f / 15.f);
      float e3 = -2.f + (float)(nb + 3) * (4.f / 15.f);
      r[0] = (_Float16)(v.x * __expf(-2.f * e0 * e0));
      r[1] = (_Float16)(v.y * __expf(-2.f * e1 * e1));
      r[2] = (_Float16)(v.z * __expf(-2.f * e2 * e2));
      r[3] = (_Float16)(v.w * __expf(-2.f * e3 * e3));
      dp[j] = r;
    }
  }
}

// ---------------- stats finalize (float partials) ----------------
// Emits isd = 1/(sd+eps) and nmi = -mu*isd so normalize is a single FMA downstream.
__global__ void stats_final_k(const float* __restrict__ ps,
                              const float* __restrict__ ps2,
                              int segs, int cols, int rows,
                              float* __restrict__ nmi, float* __restrict__ isd) {
  int c = blockIdx.x * blockDim.x + threadIdx.x;
  if (c >= cols) return;
  double s = 0.0, s2 = 0.0;
  for (int g = 0; g < segs; g++) { s += ps[(size_t)g * cols + c]; s2 += ps2[(size_t)g * cols + c]; }
  double mean = s / rows;
  double var  = (s2 - s * s / rows) / (rows - 1);   // ddof=1
  if (var < 0.0) var = 0.0;
  float sd = (float)sqrt(var);
  float iv = 1.0f / (sd + 1e-6f);
  isd[c] = iv;
  nmi[c] = -(float)mean * iv;
}

// ---------------- fused normalize+expand+GEMM+tanh + column-stats partials ----------------
// H[b, o] = tanh( sum_k basis(xn[b, k/16])_[k%16] * Cb[o, k] ),  K = C*16
// 128x128 tile, BK=64, 256 threads (2x2 waves), grid (128,4), 2 blocks/CU (R1 config —
// R8's 8-wave split tripled LDS bank conflicts via 4x A-frag re-reads; reverted).
// R9/R10 changes:
//  (1) packed expansion: v_cvt_pkrtz + v_pk_mul_f16 chain, f32 re-anchor at n=8
//      (~44 -> ~24 VALU/col, half the dep depth; f16 chain error <= 3 roundings).
//  (2) normalize folded to one FMA via (isd, nmi=-mu*isd) from stats_final.
//  (3) body reorder: gld16 first, MFMA cluster split in two with staging between
//      (frags ks0 -> MFMA ks0 -> expand(k+1) -> frags ks1 -> MFMA ks1 -> barrier)
//      so expansion VALU can run under ks0 MFMA retire instead of phase-locking.
// A: K-major LDS. B: XOR swizzle seg' = sl ^ ((row>>1)&7). setprio(1) around MFMA.
// Epilogue: fused per-block column sums of h and h^2 -> psum/psum2 for next layer's stats.
__global__ __launch_bounds__(256, 2) void kan_gemm_fused(const float* __restrict__ X,   // [B, C]
                                                         const float* __restrict__ nmi,
                                                         const float* __restrict__ isd,
                                                         const _Float16* __restrict__ Bm, // [512, C*16]
                                                         float* __restrict__ Hout,        // [B, 512]
                                                         float* __restrict__ psum,        // [128, 512]
                                                         float* __restrict__ psum2,       // [128, 512]
                                                         int C) {
  const int K = C << 4;
  const int steps = K >> 6;                 // BK = 64
  __shared__ __align__(16) _Float16 As[2][128 * 64];   // 32 KB; chunk = kseg*128 + row, kseg 0..7
  __shared__ __align__(16) _Float16 Bs[2][128 * 64];   // 32 KB; chunk = row*8 + swizzled seg
  __shared__ float Rs1[2][128], Rs2[2][128];           //  2 KB epilogue reduction
  const int tid  = threadIdx.x;
  const int w = tid >> 6, lane = tid & 63;
  const int wm = w & 1, wn = w >> 1;        // 2x2 wave grid
  const int lrow = lane & 15, quad = lane >> 4;
  const int row0 = blockIdx.x * 128;
  const int col0 = blockIdx.y * 128;

  // ---- B staging: buffer = 1024 chunks of 16B; thread owns chunks tid, tid+256, +512, +768.
  //      chunk c = row*8 + sl holds global seg = sl ^ ((row>>1)&7); rows step by 32
  //      per i so ((row>>1)&7) is invariant -> one seg for all 4 chunks.
  const int s_row = tid >> 3;               // 0..31
  const int s_sl  = tid & 7;
  const int s_seg = s_sl ^ ((s_row >> 1) & 7);
  const _Float16* gB = Bm + (size_t)(col0 + s_row) * K + s_seg * 8;

  // ---- A expansion: thread -> row = tid>>1, col-pair eh = tid&1; step k covers
  //      x-cols [4k, 4k+4); this thread expands cols 4k+2eh, 4k+2eh+1 -> ksegs 4eh..4eh+3.
  const int erow = tid >> 1, eh = tid & 1;
  const float* xp  = X   + (size_t)(row0 + erow) * C + 2 * eh;  // step k: xp[4k], xp[4k+1]
  const float* mup = nmi + 2 * eh;
  const float* isp = isd + 2 * eh;

  floatx4 acc[4][4] = {};

  // packed expansion: h[n] = Wv * g^n, n=0..15, Wv = exp(-2xn^2-8xn), g = exp((16/15)xn).
  // f32 anchors at n=0 and n=8; between anchors a packed-f16 *g^2 chain (<=3 roundings).
  auto expand_store = [&](float2 v, float2 a, float2 b, int bufi) {
#pragma unroll
    for (int h = 0; h < 2; h++) {
      float xr = h ? v.y : v.x;
      float ii = h ? a.y : a.x;
      float bb = h ? b.y : b.x;
      float xn = fminf(fmaxf(fmaf(xr, ii, bb), -3.f), 3.f);
      float Wv = __expf(fmaf(-2.f, xn, -8.f) * xn);
      float g  = __expf((16.f / 15.f) * xn);
      float g2 = g * g, g4 = g2 * g2, g8 = g4 * g4;
      fp16x2 gg = __builtin_amdgcn_cvt_pkrtz(g2, g2);
      union { fp16x2 q[4]; half8 v8; } u0, u1;
      u0.q[0] = __builtin_amdgcn_cvt_pkrtz(Wv, Wv * g);
      u0.q[1] = u0.q[0] * gg;
      u0.q[2] = u0.q[1] * gg;
      u0.q[3] = u0.q[2] * gg;
      float W8 = Wv * g8;
      u1.q[0] = __builtin_amdgcn_cvt_pkrtz(W8, W8 * g);
      u1.q[1] = u1.q[0] * gg;
      u1.q[2] = u1.q[1] * gg;
      u1.q[3] = u1.q[2] * gg;
      int ks0 = 4 * eh + 2 * h;
      *(half8*)&As[bufi][(size_t)(ks0 * 128 + erow) * 8]       = u0.v8;
      *(half8*)&As[bufi][(size_t)((ks0 + 1) * 128 + erow) * 8] = u1.v8;
    }
  };

  // ---- prologue: fill buffer 0 ----
#pragma unroll
  for (int i = 0; i < 4; i++)
    gld16(gB + (size_t)32 * i * K, &Bs[0][(size_t)(tid + 256 * i) * 8]);
  expand_store(*(const float2*)xp, *(const float2*)isp, *(const float2*)mup, 0);
  float2 xv = {}, av = {}, bv = {};
  if (steps > 1) {
    xv = *(const float2*)(xp + 4);
    av = *(const float2*)(isp + 4);
    bv = *(const float2*)(mup + 4);
  }
  __syncthreads();

  // ---- main loop: one barrier per BK=64 step ----
  for (int k = 0; k < steps; k++) {
    const int buf = k & 1, nb = buf ^ 1;
    const bool more = (k + 1 < steps);
    // (1) DMA for k+1 first: maximal in-flight time before the barrier drain
    if (more) {
#pragma unroll
      for (int i = 0; i < 4; i++)
        gld16(gB + (size_t)(k + 1) * 64 + (size_t)32 * i * K,
              &Bs[nb][(size_t)(tid + 256 * i) * 8]);
    }
    // (2) frags + MFMA ks=0
    half8 af0[4], bf0[4];
#pragma unroll
    for (int t = 0; t < 4; t++) {
      int arow = wm * 64 + t * 16 + lrow;
      af0[t] = *(const half8*)&As[buf][(size_t)(quad * 128 + arow) * 8];
      int brow = wn * 64 + t * 16 + lrow;
      int bchunk = brow * 8 + (quad ^ ((brow >> 1) & 7));
      bf0[t] = *(const half8*)&Bs[buf][(size_t)bchunk * 8];
    }
    __builtin_amdgcn_s_setprio(1);
#pragma unroll
    for (int tm = 0; tm < 4; tm++)
#pragma unroll
      for (int tn = 0; tn < 4; tn++)
        acc[tm][tn] = __builtin_amdgcn_mfma_f32_16x16x32_f16(af0[tm], bf0[tn], acc[tm][tn], 0, 0, 0);
    __builtin_amdgcn_s_setprio(0);
    // (3) staging VALU between the MFMA halves: overlaps ks0 retire
    if (more) {
      expand_store(xv, av, bv, nb);
      if (k + 2 < steps) {
        xv = *(const float2*)(xp + 4 * (k + 2));
        av = *(const float2*)(isp + 4 * (k + 2));
        bv = *(const float2*)(mup + 4 * (k + 2));
      }
    }
    // (4) frags + MFMA ks=1
    half8 af1[4], bf1[4];
#pragma unroll
    for (int t = 0; t < 4; t++) {
      int arow = wm * 64 + t * 16 + lrow;
      af1[t] = *(const half8*)&As[buf][(size_t)((4 + quad) * 128 + arow) * 8];
      int brow = wn * 64 + t * 16 + lrow;
      int bchunk = brow * 8 + ((4 + quad) ^ ((brow >> 1) & 7));
      bf1[t] = *(const half8*)&Bs[buf][(size_t)bchunk * 8];
    }
    __builtin_amdgcn_s_setprio(1);
#pragma unroll
    for (int tm = 0; tm < 4; tm++)
#pragma unroll
      for (int tn = 0; tn < 4; tn++)
        acc[tm][tn] = __builtin_amdgcn_mfma_f32_16x16x32_f16(af1[tm], bf1[tn], acc[tm][tn], 0, 0, 0);
    __builtin_amdgcn_s_setprio(0);
    __syncthreads();
  }

  // ---- epilogue: C/D layout col=lane&15, row=quad*4+reg; fused tanh + column partial sums ----
  float s1[4] = {0.f, 0.f, 0.f, 0.f}, s2v[4] = {0.f, 0.f, 0.f, 0.f};
#pragma unroll
  for (int tm = 0; tm < 4; tm++) {
#pragma unroll
    for (int tn = 0; tn < 4; tn++) {
      int gcol = col0 + wn * 64 + tn * 16 + lrow;
#pragma unroll
      for (int r = 0; r < 4; r++) {
        int grow = row0 + wm * 64 + tm * 16 + quad * 4 + r;
        float v = fast_tanh(acc[tm][tn][r]);
        Hout[(size_t)grow * H_DIM + gcol] = v;
        s1[tn] += v; s2v[tn] += v * v;
      }
    }
  }
  // reduce over quad (rows within the wave's 64-row span)
#pragma unroll
  for (int tn = 0; tn < 4; tn++) {
    s1[tn]  += __shfl_xor(s1[tn], 16);  s1[tn]  += __shfl_xor(s1[tn], 32);
    s2v[tn] += __shfl_xor(s2v[tn], 16); s2v[tn] += __shfl_xor(s2v[tn], 32);
  }
  if (quad == 0) {
#pragma unroll
    for (int tn = 0; tn < 4; tn++) {
      Rs1[wm][wn * 64 + tn * 16 + lrow] = s1[tn];
      Rs2[wm][wn * 64 + tn * 16 + lrow] = s2v[tn];
    }
  }
  __syncthreads();
  if (tid < 128) {
    psum [(size_t)blockIdx.x * H_DIM + col0 + tid] = Rs1[0][tid] + Rs1[1][tid];
    psum2[(size_t)blockIdx.x * H_DIM + col0 + tid] = Rs2[0][tid] + Rs2[1][tid];
  }
}

// ---------------- layer 3 (out dim 1) + skip, fp32, normalize fused ----------------
__global__ __launch_bounds__(256) void layer3_k(const float* __restrict__ H2,
                                                const float* __restrict__ nmi,
                                                const float* __restrict__ isd,
                                                const float* __restrict__ C3,
                                                const float* __restrict__ X,
                                                const float* __restrict__ SW,
                                                const float* __restrict__ SB,
                                                float* __restrict__ OUT) {
  int w = threadIdx.x >> 6, lane = threadIdx.x & 63;
  float Kn[NB];
#pragma unroll
  for (int n = 0; n < NB; n++) {
    float c = -2.f + (float)n * (4.f / 15.f);
    Kn[n] = __expf(-2.f * c * c);
  }
  float sb0 = SB[0];
  int row_base = blockIdx.x * 16 + w * 4;
  for (int r = 0; r < 4; r++) {
    int row = row_base + r;
    float s = 0.f;
#pragma unroll
    for (int j = 0; j < 8; j++) {
      int i = lane + 64 * j;
      float hv = H2[(size_t)row * H_DIM + i];
      float xn = fminf(fmaxf(fmaf(hv, isd[i], nmi[i]), -3.f), 3.f);
      float Wf = __expf(fmaf(-2.f, xn, -8.f) * xn);
      float gf = __expf((16.f / 15.f) * xn);
      const floatx4* cp = (const floatx4*)(C3 + (size_t)i * NB);
      floatx4 c0 = cp[0], c1 = cp[1], c2 = cp[2], c3 = cp[3];
      float p = Wf;
#pragma unroll
      for (int n = 0; n < 4; n++) { s += p * Kn[n]      * c0[n]; p *= gf; }
#pragma unroll
      for (int n = 0; n < 4; n++) { s += p * Kn[n + 4]  * c1[n]; p *= gf; }
#pragma unroll
      for (int n = 0; n < 4; n++) { s += p * Kn[n + 8]  * c2[n]; p *= gf; }
#pragma unroll
      for (int n = 0; n < 4; n++) { s += p * Kn[n + 12] * c3[n]; p *= gf; }
    }
#pragma unroll
    for (int j = 0; j < 4; j++) {
      int i = lane + 64 * j;
      s += X[(size_t)row * IN_DIM + i] * SW[i];
    }
#pragma unroll
    for (int off = 32; off > 0; off >>= 1) s += __shfl_down(s, off);
    if (lane == 0) OUT[row] = s + sb0;
  }
}

// ---------------- launcher ----------------
extern "C" void kernel_launch(void* const* d_in, const int* in_sizes, int n_in,
                              void* d_out, int out_size, void* d_ws, size_t ws_size,
                              hipStream_t stream) {
  const float* x  = (const float*)d_in[0];   // [16384, 256]
  const float* c1 = (const float*)d_in[1];   // [512, 256, 16]
  const float* c2 = (const float*)d_in[2];   // [512, 512, 16]
  const float* c3 = (const float*)d_in[3];   // [1, 512, 16]
  const float* sw = (const float*)d_in[4];   // [1, 256]
  const float* sb = (const float*)d_in[5];   // [1]
  float* out = (float*)d_out;

  const int B = B_ROWS, IN = IN_DIM, H = H_DIM;

  char* ws = (char*)d_ws;
  size_t off = 0;
  auto alloc = [&](size_t bytes) -> void* {
    void* p = ws + off;
    off += (bytes + 255) & ~(size_t)255;
    return p;
  };
  _Float16* C1h = (_Float16*)alloc((size_t)H * IN * NB * 2);  //  4 MB
  _Float16* C2h = (_Float16*)alloc((size_t)H * H  * NB * 2);  //  8 MB
  float* H1 = (float*)alloc((size_t)B * H * 4);               // 32 MB
  float* H2 = (float*)alloc((size_t)B * H * 4);               // 32 MB
  float* ps  = (float*)alloc(128 * 512 * 4);                  // 256 KB
  float* ps2 = (float*)alloc(128 * 512 * 4);
  float* nmi = (float*)alloc(512 * 4);
  float* isd = (float*)alloc(512 * 4);

  // ---- prep: x-stats partials + coeff cvt in one dispatch ----
  prep_k<<<128 + 1024, 256, 0, stream>>>(c1, C1h, (size_t)H * IN * NB / 4,
                                         c2, C2h, (size_t)H * H * NB / 4,
                                         x, ps, ps2);
  stats_final_k<<<1, 256, 0, stream>>>(ps, ps2, 32, IN, B, nmi, isd);

  // ---- layer 1 (C=256, K=4096); epilogue emits H1 column partials ----
  kan_gemm_fused<<<dim3(B / 128, 4), 256, 0, stream>>>(x, nmi, isd, C1h, H1, ps, ps2, IN);
  stats_final_k<<<2, 256, 0, stream>>>(ps, ps2, 128, H, B, nmi, isd);

  // ---- layer 2 (C=512, K=8192); epilogue emits H2 column partials ----
  kan_gemm_fused<<<dim3(B / 128, 4), 256, 0, stream>>>(H1, nmi, isd, C2h, H2, ps, ps2, H);
  stats_final_k<<<2, 256, 0, stream>>>(ps, ps2, 128, H, B, nmi, isd);

  // ---- layer 3 + skip (normalize fused) ----
  layer3_k<<<B / 16, 256, 0, stream>>>(H2, nmi, isd, c3, x, sw, sb, out);
}

// Round 5
// 454.596 us; speedup vs baseline: 1.1080x; 1.0023x over previous
//
#include <hip/hip_runtime.h>
#include <cstdint>
#include <cstddef>

// ---------------- types ----------------
typedef __attribute__((ext_vector_type(8))) _Float16 half8;   // MFMA f16 A/B frag (4 VGPRs)
typedef __attribute__((ext_vector_type(4))) _Float16 half4;
typedef __attribute__((ext_vector_type(2))) __fp16   fp16x2;  // cvt_pkrtz result type
typedef __attribute__((ext_vector_type(4))) float    floatx4; // MFMA C/D frag

static constexpr int B_ROWS = 16384;
static constexpr int IN_DIM = 256;
static constexpr int H_DIM  = 512;
static constexpr int NB     = 16;

__device__ __forceinline__ float fast_tanh(float x) {
  float ax = fabsf(x);
  float e  = __expf(2.0f * ax);             // e >= 1, inf-safe
  float t  = 1.0f - 2.0f / (e + 1.0f);
  return copysignf(t, x);
}

// async global->LDS, 16B per lane; LDS dest must be wave-uniform base + lane*16
__device__ __forceinline__ void gld16(const void* g, void* l) {
  __builtin_amdgcn_global_load_lds(
      (const __attribute__((address_space(1))) unsigned int*)g,
      (__attribute__((address_space(3))) unsigned int*)l, 16, 0, 0);
}

// ---------------- prep: x column-stats partials (blocks 0..127) + coeff cvt (blocks 128+) ----
// cvt folds K_n = exp(-2 c_n^2) into the fp16 coeffs.
__global__ __launch_bounds__(256) void prep_k(const float* __restrict__ c1, _Float16* __restrict__ d1, size_t n41,
                                              const float* __restrict__ c2, _Float16* __restrict__ d2, size_t n42,
                                              const float* __restrict__ X,
                                              float* __restrict__ ps, float* __restrict__ ps2) {
  const int bx = blockIdx.x;
  if (bx < 128) {
    // ---- stats on X: cols=256 (4 col-groups of 64), 32 row-segs of 512 ----
    int c     = (bx & 3) * 64 + (threadIdx.x & 63);
    int chunk = threadIdx.x >> 6;
    int seg   = bx >> 2;
    int r0    = seg * 512;
    double s = 0.0, s2 = 0.0;
    for (int r = r0 + chunk; r < r0 + 512; r += 4) {
      float v = X[(size_t)r * IN_DIM + c];
      s += v; s2 += (double)v * (double)v;
    }
    __shared__ float Ls[256], Ls2[256];
    Ls[threadIdx.x] = (float)s; Ls2[threadIdx.x] = (float)s2;
    __syncthreads();
    if (chunk == 0) {
      int cl = threadIdx.x;
      float a  = Ls[cl]  + Ls[cl + 64]  + Ls[cl + 128]  + Ls[cl + 192];
      float b  = Ls2[cl] + Ls2[cl + 64] + Ls2[cl + 128] + Ls2[cl + 192];
      ps [(size_t)seg * IN_DIM + c] = a;
      ps2[(size_t)seg * IN_DIM + c] = b;
    }
  } else {
    // ---- coeff conversion, grid-stride over remaining blocks ----
    size_t tot = n41 + n42;
    int nb_blocks = gridDim.x - 128;
    for (size_t i = (size_t)(bx - 128) * 256 + threadIdx.x; i < tot;
         i += (size_t)nb_blocks * 256) {
      const float4* sp; half4* dp; size_t j;
      if (i < n41) { sp = (const float4*)c1; dp = (half4*)d1; j = i; }
      else         { sp = (const float4*)c2; dp = (half4*)d2; j = i - n41; }
      float4 v = sp[j];
      int nb = (int)((j << 2) & 15);
      half4 r;
      float e0 = -2.f + (float)(nb + 0) * (4.f / 15.f);
      float e1 = -2.f + (float)(nb + 1) * (4.f / 15.f);
      float e2 = -2.f + (float)(nb + 2) * (4.f / 15.f);
      float e3 = -2.f + (float)(nb + 3) * (4.f / 15.f);
      r[0] = (_Float16)(v.x * __expf(-2.f * e0 * e0));
      r[1] = (_Float16)(v.y * __expf(-2.f * e1 * e1));
      r[2] = (_Float16)(v.z * __expf(-2.f * e2 * e2));
      r[3] = (_Float16)(v.w * __expf(-2.f * e3 * e3));
      dp[j] = r;
    }
  }
}

// ---------------- stats finalize (float partials) ----------------
// Emits isd = 1/(sd+eps) and nmi = -mu*isd so normalize is a single FMA downstream.
__global__ void stats_final_k(const float* __restrict__ ps,
                              const float* __restrict__ ps2,
                              int segs, int cols, int rows,
                              float* __restrict__ nmi, float* __restrict__ isd) {
  int c = blockIdx.x * blockDim.x + threadIdx.x;
  if (c >= cols) return;
  double s = 0.0, s2 = 0.0;
  for (int g = 0; g < segs; g++) { s += ps[(size_t)g * cols + c]; s2 += ps2[(size_t)g * cols + c]; }
  double mean = s / rows;
  double var  = (s2 - s * s / rows) / (rows - 1);   // ddof=1
  if (var < 0.0) var = 0.0;
  float sd = (float)sqrt(var);
  float iv = 1.0f / (sd + 1e-6f);
  isd[c] = iv;
  nmi[c] = -(float)mean * iv;
}

// ---------------- fused normalize+expand+GEMM+tanh + column-stats partials ----------------
// H[b, o] = tanh( sum_k basis(xn[b, k/16])_[k%16] * Cb[o, k] ),  K = C*16
// 128x128 tile, BK=64, 256 threads (2x2 waves), grid (128,4), 2 blocks/CU.
// R11: counted-vmcnt pipeline (T4). R4 post-mortem: VALU cut (37->32) with flat
// duration and MfmaUtil pinned at ~34% = the measured 2-phase-template ceiling (m233).
// The escape (m218, +38-73%) is to NEVER drain vmcnt in the main loop:
//  - Bs triple-buffered (48 KB): DMA for k+2 issued at step k, 2 steps in flight.
//  - barrier is raw s_barrier preceded by lgkmcnt(0) ONLY (no vmcnt drain).
//  - correctness of the un-drained DMA rides vmcnt ordering (m135): expand(k+1)
//    consumes x-regs loaded AFTER DMA(k+1) in program order, so the compiler's
//    dependency wait retires DMA(k+1) mid-step, before this wave's end-of-k barrier.
//    Every wave does this => after the barrier all of Bs[k+1] is resident.
//    sched_barrier(0) pins DMA-before-x-load emission order.
//  - As stays double-buffered (32 KB); total LDS exactly 80 KB -> 2 blocks/CU.
//    Epilogue reduction buffers alias As (loop's final barrier makes it dead).
// A: K-major LDS. B: XOR swizzle seg' = sl ^ ((row>>1)&7). setprio(1) around MFMA.
__global__ __launch_bounds__(256, 2) void kan_gemm_fused(const float* __restrict__ X,   // [B, C]
                                                         const float* __restrict__ nmi,
                                                         const float* __restrict__ isd,
                                                         const _Float16* __restrict__ Bm, // [512, C*16]
                                                         float* __restrict__ Hout,        // [B, 512]
                                                         float* __restrict__ psum,        // [128, 512]
                                                         float* __restrict__ psum2,       // [128, 512]
                                                         int C) {
  const int K = C << 4;
  const int steps = K >> 6;                 // BK = 64
  __shared__ __align__(16) _Float16 As[2][128 * 64];   // 32 KB; chunk = kseg*128 + row
  __shared__ __align__(16) _Float16 Bs[3][128 * 64];   // 48 KB; chunk = row*8 + swizzled seg
  const int tid  = threadIdx.x;
  const int w = tid >> 6, lane = tid & 63;
  const int wm = w & 1, wn = w >> 1;        // 2x2 wave grid
  const int lrow = lane & 15, quad = lane >> 4;
  const int row0 = blockIdx.x * 128;
  const int col0 = blockIdx.y * 128;

  // ---- B staging: buffer = 1024 chunks of 16B; thread owns chunks tid + 256*i.
  const int s_row = tid >> 3;               // 0..31
  const int s_sl  = tid & 7;
  const int s_seg = s_sl ^ ((s_row >> 1) & 7);
  const _Float16* gB = Bm + (size_t)(col0 + s_row) * K + s_seg * 8;

  // ---- A expansion: thread -> row = tid>>1, col-pair eh = tid&1
  const int erow = tid >> 1, eh = tid & 1;
  const float* xp  = X   + (size_t)(row0 + erow) * C + 2 * eh;  // step k: xp[4k], xp[4k+1]
  const float* mup = nmi + 2 * eh;
  const float* isp = isd + 2 * eh;

  floatx4 acc[4][4] = {};

  // packed expansion: h[n] = Wv * g^n; f32 anchors at n=0,8; packed-f16 *g^2 chain between.
  auto expand_store = [&](float2 v, float2 a, float2 b, int bufi) {
#pragma unroll
    for (int h = 0; h < 2; h++) {
      float xr = h ? v.y : v.x;
      float ii = h ? a.y : a.x;
      float bb = h ? b.y : b.x;
      float xn = fminf(fmaxf(fmaf(xr, ii, bb), -3.f), 3.f);
      float Wv = __expf(fmaf(-2.f, xn, -8.f) * xn);
      float g  = __expf((16.f / 15.f) * xn);
      float g2 = g * g, g4 = g2 * g2, g8 = g4 * g4;
      fp16x2 gg = __builtin_amdgcn_cvt_pkrtz(g2, g2);
      union { fp16x2 q[4]; half8 v8; } u0, u1;
      u0.q[0] = __builtin_amdgcn_cvt_pkrtz(Wv, Wv * g);
      u0.q[1] = u0.q[0] * gg;
      u0.q[2] = u0.q[1] * gg;
      u0.q[3] = u0.q[2] * gg;
      float W8 = Wv * g8;
      u1.q[0] = __builtin_amdgcn_cvt_pkrtz(W8, W8 * g);
      u1.q[1] = u1.q[0] * gg;
      u1.q[2] = u1.q[1] * gg;
      u1.q[3] = u1.q[2] * gg;
      int ks0 = 4 * eh + 2 * h;
      *(half8*)&As[bufi][(size_t)(ks0 * 128 + erow) * 8]       = u0.v8;
      *(half8*)&As[bufi][(size_t)((ks0 + 1) * 128 + erow) * 8] = u1.v8;
    }
  };

  // ---- prologue ----
  float2 x0 = *(const float2*)xp;
  float2 a0 = *(const float2*)isp;
  float2 b0 = *(const float2*)mup;
#pragma unroll
  for (int i = 0; i < 4; i++)                                   // DMA(0) -> Bs[0]
    gld16(gB + (size_t)32 * i * K, &Bs[0][(size_t)(tid + 256 * i) * 8]);
  __builtin_amdgcn_sched_barrier(0);
#pragma unroll
  for (int i = 0; i < 4; i++)                                   // DMA(1) -> Bs[1]
    gld16(gB + 64 + (size_t)32 * i * K, &Bs[1][(size_t)(tid + 256 * i) * 8]);
  __builtin_amdgcn_sched_barrier(0);
  float2 xv = *(const float2*)(xp + 4);                         // x-regs for step 1
  float2 av = *(const float2*)(isp + 4);
  float2 bv = *(const float2*)(mup + 4);
  expand_store(x0, a0, b0, 0);
  asm volatile("s_waitcnt vmcnt(7)" ::: "memory");              // DMA(0) landed
  asm volatile("s_waitcnt lgkmcnt(0)" ::: "memory");
  __builtin_amdgcn_s_barrier();
  __builtin_amdgcn_sched_barrier(0);

  // ---- main loop: raw barrier per step, vmcnt never drained ----
  int bcur = 0;                                                 // Bs buffer for step k
  for (int k = 0; k < steps; k++) {
    const int abuf = k & 1;
    const bool more  = (k + 1 < steps);
    const bool more2 = (k + 2 < steps);
    const int b2 = (bcur == 0) ? 2 : bcur - 1;                  // (k+2)%3
    if (more2) {
#pragma unroll
      for (int i = 0; i < 4; i++)                               // DMA(k+2), 2 steps of slack
        gld16(gB + (size_t)(k + 2) * 64 + (size_t)32 * i * K,
              &Bs[b2][(size_t)(tid + 256 * i) * 8]);
      __builtin_amdgcn_sched_barrier(0);
    }
    // frags + MFMA ks=0
    half8 af0[4], bf0[4];
#pragma unroll
    for (int t = 0; t < 4; t++) {
      int arow = wm * 64 + t * 16 + lrow;
      af0[t] = *(const half8*)&As[abuf][(size_t)(quad * 128 + arow) * 8];
      int brow = wn * 64 + t * 16 + lrow;
      int bchunk = brow * 8 + (quad ^ ((brow >> 1) & 7));
      bf0[t] = *(const half8*)&Bs[bcur][(size_t)bchunk * 8];
    }
    __builtin_amdgcn_s_setprio(1);
#pragma unroll
    for (int tm = 0; tm < 4; tm++)
#pragma unroll
      for (int tn = 0; tn < 4; tn++)
        acc[tm][tn] = __builtin_amdgcn_mfma_f32_16x16x32_f16(af0[tm], bf0[tn], acc[tm][tn], 0, 0, 0);
    __builtin_amdgcn_s_setprio(0);
    // staging VALU between the MFMA halves; xv consumption retires DMA(k+1) (vmcnt order)
    if (more) {
      expand_store(xv, av, bv, abuf ^ 1);
      if (more2) {
        xv = *(const float2*)(xp + 4 * (k + 2));
        av = *(const float2*)(isp + 4 * (k + 2));
        bv = *(const float2*)(mup + 4 * (k + 2));
      }
    }
    // frags + MFMA ks=1
    half8 af1[4], bf1[4];
#pragma unroll
    for (int t = 0; t < 4; t++) {
      int arow = wm * 64 + t * 16 + lrow;
      af1[t] = *(const half8*)&As[abuf][(size_t)((4 + quad) * 128 + arow) * 8];
      int brow = wn * 64 + t * 16 + lrow;
      int bchunk = brow * 8 + ((4 + quad) ^ ((brow >> 1) & 7));
      bf1[t] = *(const half8*)&Bs[bcur][(size_t)bchunk * 8];
    }
    __builtin_amdgcn_s_setprio(1);
#pragma unroll
    for (int tm = 0; tm < 4; tm++)
#pragma unroll
      for (int tn = 0; tn < 4; tn++)
        acc[tm][tn] = __builtin_amdgcn_mfma_f32_16x16x32_f16(af1[tm], bf1[tn], acc[tm][tn], 0, 0, 0);
    __builtin_amdgcn_s_setprio(0);
    asm volatile("s_waitcnt lgkmcnt(0)" ::: "memory");          // LDS writes visible; NO vmcnt drain
    __builtin_amdgcn_s_barrier();
    __builtin_amdgcn_sched_barrier(0);
    bcur = (bcur == 2) ? 0 : bcur + 1;
  }

  // ---- epilogue: C/D layout col=lane&15, row=quad*4+reg; fused tanh + column partial sums ----
  // reduction buffers alias As (dead after the loop's final barrier)
  float* Rs1 = reinterpret_cast<float*>(&As[0][0]);   // [2][128]
  float* Rs2 = Rs1 + 256;                              // [2][128]
  float s1[4] = {0.f, 0.f, 0.f, 0.f}, s2v[4] = {0.f, 0.f, 0.f, 0.f};
#pragma unroll
  for (int tm = 0; tm < 4; tm++) {
#pragma unroll
    for (int tn = 0; tn < 4; tn++) {
      int gcol = col0 + wn * 64 + tn * 16 + lrow;
#pragma unroll
      for (int r = 0; r < 4; r++) {
        int grow = row0 + wm * 64 + tm * 16 + quad * 4 + r;
        float v = fast_tanh(acc[tm][tn][r]);
        Hout[(size_t)grow * H_DIM + gcol] = v;
        s1[tn] += v; s2v[tn] += v * v;
      }
    }
  }
#pragma unroll
  for (int tn = 0; tn < 4; tn++) {
    s1[tn]  += __shfl_xor(s1[tn], 16);  s1[tn]  += __shfl_xor(s1[tn], 32);
    s2v[tn] += __shfl_xor(s2v[tn], 16); s2v[tn] += __shfl_xor(s2v[tn], 32);
  }
  if (quad == 0) {
#pragma unroll
    for (int tn = 0; tn < 4; tn++) {
      Rs1[wm * 128 + wn * 64 + tn * 16 + lrow] = s1[tn];
      Rs2[wm * 128 + wn * 64 + tn * 16 + lrow] = s2v[tn];
    }
  }
  asm volatile("s_waitcnt lgkmcnt(0)" ::: "memory");            // avoid draining Hout stores
  __builtin_amdgcn_s_barrier();
  __builtin_amdgcn_sched_barrier(0);
  if (tid < 128) {
    psum [(size_t)blockIdx.x * H_DIM + col0 + tid] = Rs1[tid] + Rs1[128 + tid];
    psum2[(size_t)blockIdx.x * H_DIM + col0 + tid] = Rs2[tid] + Rs2[128 + tid];
  }
}

// ---------------- layer 3 (out dim 1) + skip, fp32, normalize fused ----------------
__global__ __launch_bounds__(256) void layer3_k(const float* __restrict__ H2,
                                                const float* __restrict__ nmi,
                                                const float* __restrict__ isd,
                                                const float* __restrict__ C3,
                                                const float* __restrict__ X,
                                                const float* __restrict__ SW,
                                                const float* __restrict__ SB,
                                                float* __restrict__ OUT) {
  int w = threadIdx.x >> 6, lane = threadIdx.x & 63;
  float Kn[NB];
#pragma unroll
  for (int n = 0; n < NB; n++) {
    float c = -2.f + (float)n * (4.f / 15.f);
    Kn[n] = __expf(-2.f * c * c);
  }
  float sb0 = SB[0];
  int row_base = blockIdx.x * 16 + w * 4;
  for (int r = 0; r < 4; r++) {
    int row = row_base + r;
    float s = 0.f;
#pragma unroll
    for (int j = 0; j < 8; j++) {
      int i = lane + 64 * j;
      float hv = H2[(size_t)row * H_DIM + i];
      float xn = fminf(fmaxf(fmaf(hv, isd[i], nmi[i]), -3.f), 3.f);
      float Wf = __expf(fmaf(-2.f, xn, -8.f) * xn);
      float gf = __expf((16.f / 15.f) * xn);
      const floatx4* cp = (const floatx4*)(C3 + (size_t)i * NB);
      floatx4 c0 = cp[0], c1 = cp[1], c2 = cp[2], c3 = cp[3];
      float p = Wf;
#pragma unroll
      for (int n = 0; n < 4; n++) { s += p * Kn[n]      * c0[n]; p *= gf; }
#pragma unroll
      for (int n = 0; n < 4; n++) { s += p * Kn[n + 4]  * c1[n]; p *= gf; }
#pragma unroll
      for (int n = 0; n < 4; n++) { s += p * Kn[n + 8]  * c2[n]; p *= gf; }
#pragma unroll
      for (int n = 0; n < 4; n++) { s += p * Kn[n + 12] * c3[n]; p *= gf; }
    }
#pragma unroll
    for (int j = 0; j < 4; j++) {
      int i = lane + 64 * j;
      s += X[(size_t)row * IN_DIM + i] * SW[i];
    }
#pragma unroll
    for (int off = 32; off > 0; off >>= 1) s += __shfl_down(s, off);
    if (lane == 0) OUT[row] = s + sb0;
  }
}

// ---------------- launcher ----------------
extern "C" void kernel_launch(void* const* d_in, const int* in_sizes, int n_in,
                              void* d_out, int out_size, void* d_ws, size_t ws_size,
                              hipStream_t stream) {
  const float* x  = (const float*)d_in[0];   // [16384, 256]
  const float* c1 = (const float*)d_in[1];   // [512, 256, 16]
  const float* c2 = (const float*)d_in[2];   // [512, 512, 16]
  const float* c3 = (const float*)d_in[3];   // [1, 512, 16]
  const float* sw = (const float*)d_in[4];   // [1, 256]
  const float* sb = (const float*)d_in[5];   // [1]
  float* out = (float*)d_out;

  const int B = B_ROWS, IN = IN_DIM, H = H_DIM;

  char* ws = (char*)d_ws;
  size_t off = 0;
  auto alloc = [&](size_t bytes) -> void* {
    void* p = ws + off;
    off += (bytes + 255) & ~(size_t)255;
    return p;
  };
  _Float16* C1h = (_Float16*)alloc((size_t)H * IN * NB * 2);  //  4 MB
  _Float16* C2h = (_Float16*)alloc((size_t)H * H  * NB * 2);  //  8 MB
  float* H1 = (float*)alloc((size_t)B * H * 4);               // 32 MB
  float* H2 = (float*)alloc((size_t)B * H * 4);               // 32 MB
  float* ps  = (float*)alloc(128 * 512 * 4);                  // 256 KB
  float* ps2 = (float*)alloc(128 * 512 * 4);
  float* nmi = (float*)alloc(512 * 4);
  float* isd = (float*)alloc(512 * 4);

  // ---- prep: x-stats partials + coeff cvt in one dispatch ----
  prep_k<<<128 + 1024, 256, 0, stream>>>(c1, C1h, (size_t)H * IN * NB / 4,
                                         c2, C2h, (size_t)H * H * NB / 4,
                                         x, ps, ps2);
  stats_final_k<<<1, 256, 0, stream>>>(ps, ps2, 32, IN, B, nmi, isd);

  // ---- layer 1 (C=256, K=4096); epilogue emits H1 column partials ----
  kan_gemm_fused<<<dim3(B / 128, 4), 256, 0, stream>>>(x, nmi, isd, C1h, H1, ps, ps2, IN);
  stats_final_k<<<2, 256, 0, stream>>>(ps, ps2, 128, H, B, nmi, isd);

  // ---- layer 2 (C=512, K=8192); epilogue emits H2 column partials ----
  kan_gemm_fused<<<dim3(B / 128, 4), 256, 0, stream>>>(H1, nmi, isd, C2h, H2, ps, ps2, H);
  stats_final_k<<<2, 256, 0, stream>>>(ps, ps2, 128, H, B, nmi, isd);

  // ---- layer 3 + skip (normalize fused) ----
  layer3_k<<<B / 16, 256, 0, stream>>>(H2, nmi, isd, c3, x, sw, sb, out);
}